// Round 11
// baseline (530.251 us; speedup 1.0000x reference)
//
#include <hip/hip_runtime.h>
#include <hip/hip_bf16.h>

// Fused SE(3) feedforward, bf16 MFMA, fp32 accumulate.
// Round 11: register-cached A-fragments (afc[NT][NC], loaded once, reused all
// 8 chunks) at the 256-reg budget: 4 waves (256 thr), launch_bounds(256,2),
// 2 blocks/CU. G1 nn=2, G2 nn=4 (wave owns 64 d-cols). Reg peak ~228 (M=5,
// NC=4), ~196 (M=3, NC=8). R7's proven 1-barrier/chunk lH dbuf schedule.

typedef __attribute__((ext_vector_type(8))) short short8;   // 8 bf16 (MFMA A/B frag)
typedef __attribute__((ext_vector_type(4))) float f32x4;    // MFMA C/D frag

static __device__ __forceinline__ short f2bf(float f) {
  __hip_bfloat16 h = __float2bfloat16(f);
  return *reinterpret_cast<short*>(&h);
}

// ---- fused weight packing into MFMA-fragment order (bf16) ----
__global__ void pack_all_k(const float* __restrict__ w0i, const float* __restrict__ w0o,
                           const float* __restrict__ w1i, const float* __restrict__ w1o,
                           const float* __restrict__ w2i, const float* __restrict__ w2o,
                           short* __restrict__ p) {
  const int region = blockIdx.x >> 7;                 // 0..5
  const int gid = (blockIdx.x & 127) * 256 + threadIdx.x;  // 0..32767
  const int lane = gid & 63;
  const int tile = gid >> 6;
  const int gg = lane >> 4, cc = lane & 15;
  const float* w = (region == 0) ? w0i : (region == 1) ? w0o :
                   (region == 2) ? w1i : (region == 3) ? w1o :
                   (region == 4) ? w2i : w2o;
  short8 v;
  if (region & 1) {   // w_out pack: tile (kt2<32, nt2<16)
    const int nt2 = tile & 15, kt2 = tile >> 4;
#pragma unroll
    for (int j = 0; j < 8; ++j)
      v[j] = f2bf(w[(kt2 * 32 + gg * 8 + j) * 256 + nt2 * 16 + cc]);
  } else {            // w_in pack: tile (nt<64, kt<8)
    const int kt = tile & 7, nt = tile >> 3;
#pragma unroll
    for (int j = 0; j < 8; ++j)
      v[j] = f2bf(w[(kt * 32 + gg * 8 + j) * 1024 + nt * 16 + cc]);
  }
  *reinterpret_cast<short8*>(p + ((size_t)region * 262144) + gid * 8) = v;
}

// ---- fused main kernel (4 waves, CH=128, 8 chunks, reg-cached A-frags) ----
// NT token tiles of 16; tokens t = a*16 + r. GRP = norm-group over tiles
// (GRP==NT for deg>0 where a=mm; GRP==1 for deg0 at 32 rows).
// NC = number of kt-slices register-cached (rest read from lA per chunk).
// lA rows 512 B, lH rows 256 B; XOR swizzle byte ^= (t&7)<<4 (R7-proven).
template<int NT, int GRP, int OUT_M, int NC>
__global__ __launch_bounds__(256, 2)
void ff_se3_kernel(const float* __restrict__ x,
                   const short* __restrict__ wpin,
                   const short* __restrict__ wpout,
                   const float* __restrict__ scale,
                   const float* __restrict__ bias,
                   float* __restrict__ out)
{
  constexpr int T = 16 * NT;                  // tokens per block
  constexpr int R = (OUT_M == 1) ? T : 16;    // output rows per block
  extern __shared__ short lds[];              // lA T*256 + lH dbuf 2*T*128 shorts
  short* lA  = lds;
  short* lH0 = lds + T * 256;
  short* lH1 = lH0 + T * 128;

  const int tid  = threadIdx.x;
  const int lane = tid & 63;
  const int wave = tid >> 6;                  // 0..3
  const int g    = lane >> 4;
  const int lc   = lane & 15;
  const long row0 = (long)blockIdx.x * R;

  // stage x -> lA (nt float4 reads, scatter bf16 into token layout)
  for (int e4 = tid; e4 < R * 64 * OUT_M; e4 += 256) {
    const int r  = e4 / (64 * OUT_M);
    const int o4 = e4 - r * (64 * OUT_M);
    const f32x4 v = __builtin_nontemporal_load(
        reinterpret_cast<const f32x4*>(x + (row0 + r) * (256 * OUT_M) + o4 * 4));
#pragma unroll
    for (int i = 0; i < 4; ++i) {
      const int flat = o4 * 4 + i;
      const int d  = flat / OUT_M;
      const int mm = flat - d * OUT_M;
      const int t  = mm * 16 + r;
      const int byte = t * 512 + ((d * 2) ^ ((t & 7) << 4));
      lA[byte >> 1] = f2bf(v[i]);
    }
  }

  f32x4 acc_out[NT][4];                       // wave owns 64 d-cols (4 n-tiles)
#pragma unroll
  for (int a = 0; a < NT; ++a)
#pragma unroll
    for (int b = 0; b < 4; ++b) acc_out[a][b] = (f32x4)(0.f);

  __syncthreads();

  // ---- register-cache A-frags for kt < NC (A-tile is chunk-invariant) ----
  short8 afc[NT][NC];
#pragma unroll
  for (int a = 0; a < NT; ++a)
#pragma unroll
    for (int k2 = 0; k2 < NC; ++k2) {
      const int t = a * 16 + lc;
      const int byte = t * 512 + (((k2 * 32 + g * 8) * 2) ^ ((t & 7) << 4));
      afc[a][k2] = *reinterpret_cast<const short8*>(&lA[byte >> 1]);
    }

  for (int c = 0; c < 8; ++c) {   // 128-h chunks
    short* lH = (c & 1) ? lH1 : lH0;

    // scale/bias for this wave's 32 h-cols (hidden under G1)
    float sc2[2], bi2[2];
#pragma unroll
    for (int nn = 0; nn < 2; ++nn) {
      const int hgl = c * 128 + wave * 32 + nn * 16 + lc;
      sc2[nn] = scale[hgl];
      bi2[nn] = bias[hgl];
    }

    // ---- GEMM1: wave owns 32 h-cols (2 n-tiles), K=256 ----
    f32x4 acc1[NT][2];
#pragma unroll
    for (int a = 0; a < NT; ++a) { acc1[a][0] = (f32x4)(0.f); acc1[a][1] = (f32x4)(0.f); }
#pragma unroll
    for (int kt = 0; kt < 8; ++kt) {
      short8 af[NT];
#pragma unroll
      for (int a = 0; a < NT; ++a) {
        if (kt < NC) {
          af[a] = afc[a][kt];
        } else {
          const int t = a * 16 + lc;
          const int byte = t * 512 + (((kt * 32 + g * 8) * 2) ^ ((t & 7) << 4));
          af[a] = *reinterpret_cast<const short8*>(&lA[byte >> 1]);
        }
      }
      short8 bfr[2];
#pragma unroll
      for (int nn = 0; nn < 2; ++nn) {
        const int ntg = c * 8 + wave * 2 + nn;
        bfr[nn] = *reinterpret_cast<const short8*>(wpin + ((ntg * 8 + kt) * 64 + lane) * 8);
      }
#pragma unroll
      for (int a = 0; a < NT; ++a)
#pragma unroll
        for (int nn = 0; nn < 2; ++nn)
          acc1[a][nn] = __builtin_amdgcn_mfma_f32_16x16x32_bf16(af[a], bfr[nn], acc1[a][nn], 0, 0, 0);
    }

    // ---- nonlinearity: per-(row,h) norm over its GRP tiles + gelu gate ----
#pragma unroll
    for (int nn = 0; nn < 2; ++nn) {
      const float sc = sc2[nn];
      const float bi = bi2[nn];
#pragma unroll
      for (int reg = 0; reg < 4; ++reg) {
#pragma unroll
        for (int gi = 0; gi < NT / GRP; ++gi) {
          float ns = 0.f;
#pragma unroll
          for (int k = 0; k < GRP; ++k) {
            const float h = acc1[gi * GRP + k][nn][reg];
            ns += h * h;
          }
          ns = fmaxf(ns, 1e-24f);
          const float rn  = __builtin_amdgcn_rsqf(ns);
          const float nrm = ns * rn;
          const float z   = fmaf(nrm, sc, bi);
          float u2 = 2.f * z * fmaf(0.0356774081f * z, z, 0.7978845608f);
          u2 = fminf(u2, 30.f);
          const float e  = __expf(u2);
          const float th = (e - 1.f) * __builtin_amdgcn_rcpf(e + 1.f);
          const float fac = 0.5f * (1.f + th) * z * rn;
          const int tl  = g * 4 + reg;
          const int col = wave * 32 + nn * 16 + lc;
#pragma unroll
          for (int k = 0; k < GRP; ++k) {
            const int a = gi * GRP + k;
            const int t = a * 16 + tl;
            const int byte = t * 256 + ((col * 2) ^ ((t & 7) << 4));
            lH[byte >> 1] = f2bf(acc1[a][nn][reg] * fac);
          }
        }
      }
    }

    __syncthreads();   // the ONLY barrier per chunk (R7-proven dbuf ordering)

    // ---- GEMM2 partial: wave owns d-cols [wave*64, +64), chunk K=128 ----
#pragma unroll
    for (int kk = 0; kk < 4; ++kk) {
      short8 b2[4];
#pragma unroll
      for (int nn = 0; nn < 4; ++nn) {
        const int tile = (c * 4 + kk) * 16 + wave * 4 + nn;
        b2[nn] = *reinterpret_cast<const short8*>(wpout + (tile * 64 + lane) * 8);
      }
#pragma unroll
      for (int a = 0; a < NT; ++a) {
        const int t = a * 16 + lc;
        const int byte = t * 256 + (((kk * 32 + g * 8) * 2) ^ ((t & 7) << 4));
        const short8 a2 = *reinterpret_cast<const short8*>(&lH[byte >> 1]);
#pragma unroll
        for (int nn = 0; nn < 4; ++nn)
          acc_out[a][nn] = __builtin_amdgcn_mfma_f32_16x16x32_bf16(a2, b2[nn], acc_out[a][nn], 0, 0, 0);
      }
    }
    // nonlin(c+1) writes the OTHER lH buffer; nonlin(c+2) re-writes this one
    // only after barrier c+1, which all G2(c) readers reach first.
  }

  // ---- epilogue: scatter acc to LDS fp32 (exactly T*256 floats), flat copy ----
  __syncthreads();                       // all G2(7) lH reads done
  float* ldsF = reinterpret_cast<float*>(lds);
  constexpr int RW = 256 * OUT_M;        // floats per output row
  if constexpr (OUT_M == 1) {
#pragma unroll
    for (int a = 0; a < NT; ++a)
#pragma unroll
      for (int nn = 0; nn < 4; ++nn) {
        const int d = wave * 64 + nn * 16 + lc;
#pragma unroll
        for (int reg = 0; reg < 4; ++reg) {
          const int t = a * 16 + g * 4 + reg;
          ldsF[t * RW + d] = acc_out[a][nn][reg];
        }
      }
  } else {
#pragma unroll
    for (int mm = 0; mm < NT; ++mm)
#pragma unroll
      for (int nn = 0; nn < 4; ++nn) {
        const int d = wave * 64 + nn * 16 + lc;
#pragma unroll
        for (int reg = 0; reg < 4; ++reg) {
          const int r = g * 4 + reg;
          ldsF[r * RW + d * OUT_M + mm] = acc_out[mm][nn][reg];
        }
      }
  }
  __syncthreads();
  float* obase = out + row0 * RW;
  constexpr int NF4 = (R * RW) / 4;
  for (int i = tid; i < NF4; i += 256) {
    const f32x4 v = *reinterpret_cast<const f32x4*>(&ldsF[i * 4]);
    __builtin_nontemporal_store(v, reinterpret_cast<f32x4*>(obase) + i);
  }
}

extern "C" void kernel_launch(void* const* d_in, const int* in_sizes, int n_in,
                              void* d_out, int out_size, void* d_ws, size_t ws_size,
                              hipStream_t stream)
{
  // d_in order per setup_inputs: (x, w_in, scale, bias, w_out) x degree 0..2
  short* ws = (short*)d_ws;                 // 6 * 512KB = 3MB
  const size_t WSZ = 262144;                // shorts per packed matrix
  float* outf = (float*)d_out;
  const size_t out_off[3] = {0, 4194304, 16777216};  // y0|y1|y2 concat (m=1,3,5)

  pack_all_k<<<768, 256, 0, stream>>>(
      (const float*)d_in[1],  (const float*)d_in[4],
      (const float*)d_in[6],  (const float*)d_in[9],
      (const float*)d_in[11], (const float*)d_in[14], ws);

  // deg0 (m=1): 32 rows/block, full A-cache (NC=8); LDS 32 KB, ~4 blocks/CU
  ff_se3_kernel<2, 1, 1, 8><<<512, 256, 32768, stream>>>(
      (const float*)d_in[0], ws + 0 * WSZ, ws + 1 * WSZ,
      (const float*)d_in[2], (const float*)d_in[3], outf + out_off[0]);

  // deg1 (m=3): full A-cache (NC=8, G1 LDS reads = 0); LDS 48 KB
  ff_se3_kernel<3, 3, 3, 8><<<1024, 256, 49152, stream>>>(
      (const float*)d_in[5], ws + 2 * WSZ, ws + 3 * WSZ,
      (const float*)d_in[7], (const float*)d_in[8], outf + out_off[1]);

  // deg2 (m=5): half A-cache (NC=4, reg peak ~228); LDS 80 KB, 2 blocks/CU
  ff_se3_kernel<5, 5, 5, 4><<<1024, 256, 81920, stream>>>(
      (const float*)d_in[10], ws + 4 * WSZ, ws + 5 * WSZ,
      (const float*)d_in[12], (const float*)d_in[13], outf + out_off[2]);
}

// Round 12
// 311.173 us; speedup vs baseline: 1.7040x; 1.7040x over previous
//
#include <hip/hip_runtime.h>
#include <hip/hip_bf16.h>

// Fused SE(3) feedforward, bf16 MFMA 32x32x16, fp32 accumulate.
// Round 12: switch both GEMMs to 32x32x16 (2x FLOP per LDS byte - the LDS
// read pipe was R7's wall). Tokens padded to 32-multiples (zeros; norms
// unaffected). 4 waves, CH=128, R4-proven 2-barrier chunk. acc regs:
// M=5 144, M=3 96, M=1 48 (< R6-proven 248 total budget).

typedef __attribute__((ext_vector_type(8))) short short8;   // 8 bf16 (MFMA A/B frag)
typedef __attribute__((ext_vector_type(4))) float f32x4;
typedef __attribute__((ext_vector_type(16))) float f32x16;  // 32x32 MFMA C/D frag

static __device__ __forceinline__ short f2bf(float f) {
  __hip_bfloat16 h = __float2bfloat16(f);
  return *reinterpret_cast<short*>(&h);
}

// ---- weight packing into 32-wide MFMA-fragment order (bf16) ----
// region r = blockIdx.x>>7: r=2*dg+0 -> w_in(dg), r=2*dg+1 -> w_out(dg).
// w_in  [256 k][1024 h]: tile (nt<32, kt<16): elem j of lane l =
//   w_in[kt*16 + (l>>5)*8 + j][nt*32 + (l&31)], flat = ((nt*16+kt)*64+l)*8+j
// w_out [1024 k][256 d]: tile (kt2<64, nt2<8): elem j of lane l =
//   w_out[kt2*16 + (l>>5)*8 + j][nt2*32 + (l&31)], flat = ((kt2*8+nt2)*64+l)*8+j
__global__ void pack_all_k(const float* __restrict__ w0i, const float* __restrict__ w0o,
                           const float* __restrict__ w1i, const float* __restrict__ w1o,
                           const float* __restrict__ w2i, const float* __restrict__ w2o,
                           short* __restrict__ p) {
  const int region = blockIdx.x >> 7;                 // 0..5
  const int gid = (blockIdx.x & 127) * 256 + threadIdx.x;  // 0..32767
  const int lane = gid & 63;
  const int tile = gid >> 6;                          // 0..511
  const int hi = lane >> 5, cc = lane & 31;
  const float* w = (region == 0) ? w0i : (region == 1) ? w0o :
                   (region == 2) ? w1i : (region == 3) ? w1o :
                   (region == 4) ? w2i : w2o;
  short8 v;
  if (region & 1) {   // w_out: kt2 = tile>>3 (0..63), nt2 = tile&7
    const int nt2 = tile & 7, kt2 = tile >> 3;
#pragma unroll
    for (int j = 0; j < 8; ++j)
      v[j] = f2bf(w[(kt2 * 16 + hi * 8 + j) * 256 + nt2 * 32 + cc]);
  } else {            // w_in: nt = tile>>4 (0..31), kt = tile&15
    const int kt = tile & 15, nt = tile >> 4;
#pragma unroll
    for (int j = 0; j < 8; ++j)
      v[j] = f2bf(w[(kt * 16 + hi * 8 + j) * 1024 + nt * 32 + cc]);
  }
  *reinterpret_cast<short8*>(p + ((size_t)region * 262144) + gid * 8) = v;
}

// ---- fused main kernel (4 waves, CH=128, 32x32x16) ----
// MT = 32-token tiles; tokens t = mm*16 + r (M>1) padded to PT=32*MT with
// zeros, or t = r (M=1, RR=32 rows). 32x32 C-layout: col=lane&31,
// row=(reg&3)+8*(reg>>2)+4*(lane>>5). A/B frag: row/col=lane&31,
// k=(lane>>5)*8+j (self-consistent A/B packing). Swizzle byte ^= (t&7)<<4.
template<int MT, int OUT_M, int RR, bool DX>
__global__ __launch_bounds__(256, 2)
void ff_se3_kernel(const float* __restrict__ x,
                   const short* __restrict__ wpin,
                   const short* __restrict__ wpout,
                   const float* __restrict__ scale,
                   const float* __restrict__ bias,
                   float* __restrict__ out)
{
  constexpr int PT = 32 * MT;                   // padded tokens
  constexpr int NHALF = (OUT_M == 5) ? 2 : 1;   // epilogue passes
  constexpr int RP = RR / NHALF;                // rows per epilogue pass
  extern __shared__ short lds[];                // lA PT*256 (M>1) + lH PT*128 shorts
  short* lA = lds;
  short* lH = DX ? lds : (lds + PT * 256);

  const int tid  = threadIdx.x;
  const int lane = tid & 63;
  const int wave = tid >> 6;                    // 0..3
  const int hi   = lane >> 5;
  const int col  = lane & 31;
  const long row0 = (long)blockIdx.x * RR;

  if constexpr (!DX) {
    // stage real tokens (float4 reads, scatter bf16 into token layout)
    for (int e4 = tid; e4 < RR * 64 * OUT_M; e4 += 256) {
      const int r  = e4 / (64 * OUT_M);
      const int o4 = e4 - r * (64 * OUT_M);
      const f32x4 v = __builtin_nontemporal_load(
          reinterpret_cast<const f32x4*>(x + (row0 + r) * (256 * OUT_M) + o4 * 4));
#pragma unroll
      for (int i = 0; i < 4; ++i) {
        const int flat = o4 * 4 + i;
        const int d  = flat / OUT_M;
        const int mm = flat - d * OUT_M;
        const int t  = mm * 16 + r;
        const int byte = t * 512 + ((d * 2) ^ ((t & 7) << 4));
        lA[byte >> 1] = f2bf(v[i]);
      }
    }
    // zero the pad tokens [16*OUT_M, PT) (whole rows -> swizzle-invariant)
    constexpr int PAD8 = (PT - 16 * OUT_M) * 32;   // short8 units
    const short8 z = {0, 0, 0, 0, 0, 0, 0, 0};
    for (int i = tid; i < PAD8; i += 256)
      *reinterpret_cast<short8*>(lA + (16 * OUT_M) * 256 + i * 8) = z;
  }

  f32x16 acc_out[MT][2];                        // wave owns 64 d (2 d32-tiles)
#pragma unroll
  for (int a = 0; a < MT; ++a) { acc_out[a][0] = (f32x16)(0.f); acc_out[a][1] = (f32x16)(0.f); }

  if constexpr (!DX) __syncthreads();

  for (int c = 0; c < 8; ++c) {   // 128-h chunks
    const int hgl = c * 128 + wave * 32 + col;
    const float sc = scale[hgl];
    const float bi = bias[hgl];

    // ---- GEMM1: wave owns 32 h-cols (1 n32-tile), K=256 (16 k16-slices) ----
    f32x16 acc1[MT];
#pragma unroll
    for (int a = 0; a < MT; ++a) acc1[a] = (f32x16)(0.f);
#pragma unroll
    for (int kt = 0; kt < 16; ++kt) {
      short8 af[MT];
#pragma unroll
      for (int a = 0; a < MT; ++a) {
        if constexpr (DX) {   // M=1: direct from x (d contiguous), 32KB slab
          const float* xp = x + (row0 + col) * 256 + kt * 16 + hi * 8;
          const f32x4 p0 = *reinterpret_cast<const f32x4*>(xp);
          const f32x4 p1 = *reinterpret_cast<const f32x4*>(xp + 4);
          short8 t8;
#pragma unroll
          for (int j = 0; j < 4; ++j) { t8[j] = f2bf(p0[j]); t8[4 + j] = f2bf(p1[j]); }
          af[a] = t8;
        } else {
          const int t = a * 32 + col;
          const int byte = t * 512 + (((kt * 16 + hi * 8) * 2) ^ ((t & 7) << 4));
          af[a] = *reinterpret_cast<const short8*>(&lA[byte >> 1]);
        }
      }
      const int ntg = c * 4 + wave;             // global n32-tile 0..31
      const short8 bfr = *reinterpret_cast<const short8*>(wpin + ((ntg * 16 + kt) * 64 + lane) * 8);
#pragma unroll
      for (int a = 0; a < MT; ++a)
        acc1[a] = __builtin_amdgcn_mfma_f32_32x32x16_bf16(af[a], bfr, acc1[a], 0, 0, 0);
    }

    __syncthreads();   // BARa: previous chunk's G2 readers done before lH write

    // ---- nonlinearity (per-lane: full mm-group is lane-local) ----
    const int hl = wave * 32 + col;             // h col within chunk
    if constexpr (DX) {
#pragma unroll
      for (int reg = 0; reg < 16; ++reg) {
        const int t = (reg & 3) + 8 * (reg >> 2) + 4 * hi;   // row 0..31
        const float h = acc1[0][reg];
        const float ns = fmaxf(h * h, 1e-24f);
        const float rn  = __builtin_amdgcn_rsqf(ns);
        const float nrm = ns * rn;
        const float z   = fmaf(nrm, sc, bi);
        float u2 = 2.f * z * fmaf(0.0356774081f * z, z, 0.7978845608f);
        u2 = fminf(u2, 30.f);
        const float e  = __expf(u2);
        const float th = (e - 1.f) * __builtin_amdgcn_rcpf(e + 1.f);
        const float fac = 0.5f * (1.f + th) * z * rn;
        const int byte = t * 256 + ((hl * 2) ^ ((t & 7) << 4));
        lH[byte >> 1] = f2bf(h * fac);
      }
    } else {
#pragma unroll
      for (int q = 0; q < 2; ++q)
#pragma unroll
        for (int c4 = 0; c4 < 4; ++c4) {
          const int rl = c4 + 4 * q;            // reg for row r (mm even half)
          const int r  = c4 + 8 * q + 4 * hi;   // token row 0..15
          float ns = 0.f;
#pragma unroll
          for (int a = 0; a < MT; ++a)
            ns += acc1[a][rl] * acc1[a][rl] + acc1[a][rl + 8] * acc1[a][rl + 8];
          ns = fmaxf(ns, 1e-24f);
          const float rn  = __builtin_amdgcn_rsqf(ns);
          const float nrm = ns * rn;
          const float z   = fmaf(nrm, sc, bi);
          float u2 = 2.f * z * fmaf(0.0356774081f * z, z, 0.7978845608f);
          u2 = fminf(u2, 30.f);
          const float e  = __expf(u2);
          const float th = (e - 1.f) * __builtin_amdgcn_rcpf(e + 1.f);
          const float fac = 0.5f * (1.f + th) * z * rn;
#pragma unroll
          for (int a = 0; a < MT; ++a)
#pragma unroll
            for (int h2 = 0; h2 < 2; ++h2) {
              const int t = (2 * a + h2) * 16 + r;          // incl. pad mm (zeros)
              const int byte = t * 256 + ((hl * 2) ^ ((t & 7) << 4));
              lH[byte >> 1] = f2bf(acc1[a][rl + 8 * h2] * fac);
            }
        }
    }

    __syncthreads();   // BARb: lH ready

    // ---- GEMM2 partial: wave owns d [wave*64, +64), chunk K=128 (8 slices) ----
#pragma unroll
    for (int kk = 0; kk < 8; ++kk) {
      short8 a2[MT];
#pragma unroll
      for (int a = 0; a < MT; ++a) {
        const int t = a * 32 + col;
        const int byte = t * 256 + (((kk * 16 + hi * 8) * 2) ^ ((t & 7) << 4));
        a2[a] = *reinterpret_cast<const short8*>(&lH[byte >> 1]);
      }
#pragma unroll
      for (int dn = 0; dn < 2; ++dn) {
        const int kt2 = c * 8 + kk;             // global k16-slice 0..63
        const int nt2 = wave * 2 + dn;          // d32-tile 0..7
        const short8 b2 = *reinterpret_cast<const short8*>(wpout + ((kt2 * 8 + nt2) * 64 + lane) * 8);
#pragma unroll
        for (int a = 0; a < MT; ++a)
          acc_out[a][dn] = __builtin_amdgcn_mfma_f32_32x32x16_bf16(a2[a], b2, acc_out[a][dn], 0, 0, 0);
      }
    }
  }

  // ---- epilogue: scatter acc to LDS fp32, coalesced nt-store ----
  float* ldsF = reinterpret_cast<float*>(lds);
  constexpr int RW = 256 * OUT_M;               // floats per output row
#pragma unroll
  for (int half = 0; half < NHALF; ++half) {
    __syncthreads();                            // lH/lds readers (or prev copy) done
#pragma unroll
    for (int a = 0; a < MT; ++a)
#pragma unroll
      for (int dn = 0; dn < 2; ++dn)
#pragma unroll
        for (int reg = 0; reg < 16; ++reg) {
          const int r32 = (reg & 3) + 8 * (reg >> 2) + 4 * hi;
          const int t = a * 32 + r32;
          const int d = wave * 64 + dn * 32 + col;
          if constexpr (DX) {
            ldsF[t * RW + d] = acc_out[a][dn][reg];
          } else {
            const int mm = t >> 4;
            const int r  = t & 15;
            if (mm < OUT_M && (NHALF == 1 || (r >> 3) == half))
              ldsF[(r & (RP - 1)) * RW + d * OUT_M + mm] = acc_out[a][dn][reg];
          }
        }
    __syncthreads();
    constexpr int NF4 = RP * RW / 4;
    float* obase = out + (row0 + half * RP) * RW;
    for (int i = tid; i < NF4; i += 256) {
      const f32x4 v = *reinterpret_cast<const f32x4*>(&ldsF[i * 4]);
      __builtin_nontemporal_store(v, reinterpret_cast<f32x4*>(obase) + i);
    }
  }
}

extern "C" void kernel_launch(void* const* d_in, const int* in_sizes, int n_in,
                              void* d_out, int out_size, void* d_ws, size_t ws_size,
                              hipStream_t stream)
{
  // d_in order per setup_inputs: (x, w_in, scale, bias, w_out) x degree 0..2
  short* ws = (short*)d_ws;                 // 6 * 512KB = 3MB
  const size_t WSZ = 262144;                // shorts per packed matrix
  float* outf = (float*)d_out;
  const size_t out_off[3] = {0, 4194304, 16777216};  // y0|y1|y2 concat (m=1,3,5)

  pack_all_k<<<768, 256, 0, stream>>>(
      (const float*)d_in[1],  (const float*)d_in[4],
      (const float*)d_in[6],  (const float*)d_in[9],
      (const float*)d_in[11], (const float*)d_in[14], ws);

  // deg0 (m=1): 32 rows/block, direct-x, 1 token tile; LDS 32 KB (5 blocks/CU)
  ff_se3_kernel<1, 1, 32, true><<<512, 256, 32768, stream>>>(
      (const float*)d_in[0], ws + 0 * WSZ, ws + 1 * WSZ,
      (const float*)d_in[2], (const float*)d_in[3], outf + out_off[0]);

  // deg1 (m=3): 2 token tiles (64 tokens, mm3 pad); LDS 48 KB (3 blocks/CU)
  ff_se3_kernel<2, 3, 16, false><<<1024, 256, 49152, stream>>>(
      (const float*)d_in[5], ws + 2 * WSZ, ws + 3 * WSZ,
      (const float*)d_in[7], (const float*)d_in[8], outf + out_off[1]);

  // deg2 (m=5): 3 token tiles (96 tokens, mm5 pad); LDS 72 KB (2 blocks/CU)
  ff_se3_kernel<3, 5, 16, false><<<1024, 256, 73728, stream>>>(
      (const float*)d_in[10], ws + 4 * WSZ, ws + 5 * WSZ,
      (const float*)d_in[12], (const float*)d_in[13], outf + out_off[2]);
}